// Round 1
// 1589.131 us; speedup vs baseline: 1.2262x; 1.2262x over previous
//
#include <hip/hip_runtime.h>

// Problem dims (fixed by reference setup_inputs):
// B=2, S=2048, H=4096, NH=32, NS=100, D=64
#define Bq 2
#define Sq 2048
#define Hq 4096
#define NHq 32
#define NSq 100
#define Dq 64

#define ROWS (Bq * Sq)          // 4096 total (b,s) rows
#define KSPLIT 8                // k-split blocks for q-projection
#define KRANGE (Hq / KSPLIT)    // 512
#define KC 64                   // K-chunk staged in LDS
#define RB 128                  // rows per q-projection block
#define LDP (KC + 4)            // padded LDS row stride (68 words: +4-bank rotation per row)

// ---------------------------------------------------------------------------
// K1: partial entropy of head-averaged primary attention.
// Each block handles one (b,s) row HALF (1024 of 2048 columns) across all 32
// heads: 8192 blocks, 32 float4 loads/thread, unroll 8 -> bounded VGPR and
// ~8 resident blocks/CU so the 1.07 GB paw stream stays HBM-bound.
// Gate math moved to k_scores (needs both halves).
// ---------------------------------------------------------------------------
__global__ __launch_bounds__(256) void k_entropy_part(
    const float* __restrict__ paw, float* __restrict__ ent_ws) {
  const int blk = blockIdx.x;          // 0..8191 = bs*2 + jh
  const int bs = blk >> 1;
  const int jh = blk & 1;
  const int b = bs >> 11;              // /2048
  const int s = bs & 2047;
  const int t = threadIdx.x;

  const float4* base = reinterpret_cast<const float4*>(paw);
  long idx = ((long)(b * NHq) * Sq + s) * (Sq / 4) + jh * 256 + t;
  const long hstep = (long)Sq * (Sq / 4);   // per-head stride in float4

  float ax = 0.f, ay = 0.f, az = 0.f, aw = 0.f;
#pragma unroll 8
  for (int h = 0; h < NHq; ++h) {
    const float4 v = base[idx];
    ax += v.x; ay += v.y; az += v.z; aw += v.w;
    idx += hstep;
  }

  const float inv = 1.f / 32.f;
  float e = 0.f, y;
  y = ax * inv; e -= y * __logf(y + 1e-10f);
  y = ay * inv; e -= y * __logf(y + 1e-10f);
  y = az * inv; e -= y * __logf(y + 1e-10f);
  y = aw * inv; e -= y * __logf(y + 1e-10f);

#pragma unroll
  for (int off = 32; off > 0; off >>= 1) e += __shfl_down(e, off, 64);
  __shared__ float red[4];
  if ((t & 63) == 0) red[t >> 6] = e;
  __syncthreads();
  if (t == 0) ent_ws[blk] = red[0] + red[1] + red[2] + red[3];
}

// ---------------------------------------------------------------------------
// K2: q-projection as a tiled GEMM: [4096 x 4096] x [4096 x 64]^T.
// Grid 32 rowblocks x 8 ksplit = 256 blocks (full chip). Block = 128 rows x
// 64 d x 512 k. Thread tile 8r x 4d; interleaved mappings (row = ri*16+rg,
// d = dg+di*16) put each instruction's 4 distinct LDS addresses on distinct
// bank quads -> conflict-free ds_read_b128. Replaces the old per-lane W_q
// streaming (64 distinct lines/instruction, L1 thrash, ~4x L2 over-read).
// ---------------------------------------------------------------------------
__global__ __launch_bounds__(256) void k_qproj(
    const float* __restrict__ hs, const float* __restrict__ Wq,
    float* __restrict__ qpart) {
  const int rblk = blockIdx.x;         // 0..31
  const int ksl  = blockIdx.y;         // 0..7
  const int t = threadIdx.x;
  const int r0 = rblk * RB;
  const int k0 = ksl * KRANGE;
  const int dg = t & 15;               // d group: d = dg + di*16
  const int rg = t >> 4;               // row group: row = ri*16 + rg

  __shared__ float shs[RB][LDP];       // 128 x 68 floats = 34.8 KB
  __shared__ float swq[Dq][LDP];       // 64 x 68 floats  = 17.4 KB

  float acc[8][4];
#pragma unroll
  for (int i = 0; i < 8; ++i)
#pragma unroll
    for (int j = 0; j < 4; ++j) acc[i][j] = 0.f;

  const float4* hs4 = reinterpret_cast<const float4*>(hs);
  const float4* wq4 = reinterpret_cast<const float4*>(Wq);

  for (int c = 0; c < KRANGE / KC; ++c) {       // 8 chunks of 64 k
    const int kc4 = (k0 + c * KC) >> 2;         // float4 offset in H
    // stage hs tile: 128 rows x 64 k = 2048 float4, 8 per thread, coalesced
#pragma unroll
    for (int i = 0; i < 8; ++i) {
      const int idx = i * 256 + t;
      const int row = idx >> 4, col4 = idx & 15;
      const float4 v = hs4[(long)(r0 + row) * (Hq / 4) + kc4 + col4];
      *reinterpret_cast<float4*>(&shs[row][col4 * 4]) = v;
    }
    // stage W_q tile: 64 rows x 64 k = 1024 float4, 4 per thread, coalesced
#pragma unroll
    for (int i = 0; i < 4; ++i) {
      const int idx = i * 256 + t;
      const int d = idx >> 4, col4 = idx & 15;
      const float4 v = wq4[(long)d * (Hq / 4) + kc4 + col4];
      *reinterpret_cast<float4*>(&swq[d][col4 * 4]) = v;
    }
    __syncthreads();

#pragma unroll 4
    for (int kk = 0; kk < KC; kk += 4) {
      const float4 wv0 = *reinterpret_cast<const float4*>(&swq[dg     ][kk]);
      const float4 wv1 = *reinterpret_cast<const float4*>(&swq[dg + 16][kk]);
      const float4 wv2 = *reinterpret_cast<const float4*>(&swq[dg + 32][kk]);
      const float4 wv3 = *reinterpret_cast<const float4*>(&swq[dg + 48][kk]);
#pragma unroll
      for (int ri = 0; ri < 8; ++ri) {
        const float4 hv = *reinterpret_cast<const float4*>(&shs[ri * 16 + rg][kk]);
        acc[ri][0] += hv.x * wv0.x + hv.y * wv0.y + hv.z * wv0.z + hv.w * wv0.w;
        acc[ri][1] += hv.x * wv1.x + hv.y * wv1.y + hv.z * wv1.z + hv.w * wv1.w;
        acc[ri][2] += hv.x * wv2.x + hv.y * wv2.y + hv.z * wv2.z + hv.w * wv2.w;
        acc[ri][3] += hv.x * wv3.x + hv.y * wv3.y + hv.z * wv3.z + hv.w * wv3.w;
      }
    }
    __syncthreads();
  }

  // store partial q: qpart[ksl][r0 + ri*16 + rg][dg + di*16]
  float* qp = qpart + ((long)ksl * ROWS + r0) * Dq;
#pragma unroll
  for (int ri = 0; ri < 8; ++ri) {
    const int r = ri * 16 + rg;
#pragma unroll
    for (int di = 0; di < 4; ++di)
      qp[r * Dq + dg + di * 16] = acc[ri][di];
  }
}

// ---------------------------------------------------------------------------
// K2b: reduce the 8 k-split partials -> q, scores vs 100 aux keys, softmax,
// gate (from the two entropy halves) folded into the stored weights.
// 4096 blocks x 128 threads, trivially light.
// ---------------------------------------------------------------------------
__global__ __launch_bounds__(128) void k_scores(
    const float* __restrict__ qpart, const float* __restrict__ ak,
    const float* __restrict__ rel, const float* __restrict__ ent_ws,
    const float* __restrict__ gw1p, const float* __restrict__ gbp,
    float* __restrict__ attn_ws) {
  const int row = blockIdx.x;          // 0..4095
  const int t = threadIdx.x;           // 0..127

  __shared__ float sq[Dq];
  __shared__ float ssc[128];
  __shared__ float sgate;

  if (t < Dq) {
    float q = 0.f;
#pragma unroll
    for (int ks = 0; ks < KSPLIT; ++ks)
      q += qpart[((long)ks * ROWS + row) * Dq + t];
    sq[t] = q;
  }
  if (t == 64) {
    const float ent = ent_ws[row * 2] + ent_ws[row * 2 + 1];
    float g = 1.f / (1.f + __expf(-(gw1p[0] * ent + gbp[0])));
    if (ent < 0.5f) g = 0.f;
    else if (ent > 2.0f) g = fminf(g, 0.8f);
    sgate = g;
  }
  if (t >= NSq) ssc[t] = -1e30f;       // pad 100..127 for the softmax
  __syncthreads();

  if (t < NSq) {
    const float4* a4 = reinterpret_cast<const float4*>(ak) + t * (Dq / 4);
    const float4* q4 = reinterpret_cast<const float4*>(sq);
    float acc = 0.f;
#pragma unroll
    for (int i = 0; i < Dq / 4; ++i) {
      const float4 a = a4[i];
      const float4 q = q4[i];
      acc += a.x * q.x + a.y * q.y + a.z * q.z + a.w * q.w;
    }
    ssc[t] = acc * 0.125f + __logf(rel[t] + 1e-10f);
  }
  __syncthreads();

  if (t < 64) {
    const float s0 = ssc[t];
    const float s1 = ssc[t + 64];
    float m = fmaxf(s0, s1);
#pragma unroll
    for (int off = 1; off < 64; off <<= 1) m = fmaxf(m, __shfl_xor(m, off, 64));
    const float p0 = __expf(s0 - m);
    const float p1 = __expf(s1 - m);
    float sum = p0 + p1;
#pragma unroll
    for (int off = 1; off < 64; off <<= 1) sum += __shfl_xor(sum, off, 64);
    const float scale = sgate / sum;   // gate folded in
    float* arow = attn_ws + (long)row * NSq;
    arow[t] = p0 * scale;
    if (t + 64 < NSq) arow[t + 64] = p1 * scale;
  }
}

// ---------------------------------------------------------------------------
// K3: fused = pao + sum_n attn_ws[row][n] * aux_values[n][:].
// Weights are BLOCK-UNIFORM -> read via uniform addresses so the compiler
// emits s_load_dwordx4 into SGPRs (zero LDS/VALU issue cost; v_fmac takes
// the SGPR broadcast operand). No LDS, no barriers. VALU-bound ~21 us.
// ---------------------------------------------------------------------------
__global__ __launch_bounds__(256) void k_aux_fuse(
    const float* __restrict__ av, const float* __restrict__ pao,
    const float* __restrict__ attn_ws, float* __restrict__ out) {
  const int ht = blockIdx.x;           // 0..3   (1024-column tile)
  const int rb = blockIdx.y;           // 0..255 (16-row block)
  const int t = threadIdx.x;
  const int r0 = rb * 16;
  const int c4 = ht * 256 + t;         // float4 column 0..1023

  const float4* av4 = reinterpret_cast<const float4*>(av);
  const float* w = attn_ws + (long)r0 * NSq;   // uniform base -> scalar loads

  float4 acc[16];
#pragma unroll
  for (int r = 0; r < 16; ++r) acc[r] = make_float4(0.f, 0.f, 0.f, 0.f);

  for (int n = 0; n < NSq; n += 4) {
#pragma unroll
    for (int j = 0; j < 4; ++j) {
      const float4 v = av4[(long)(n + j) * (Hq / 4) + c4];
#pragma unroll
      for (int r = 0; r < 16; ++r) {
        const float wv = w[r * NSq + n + j];   // uniform -> s_load
        acc[r].x += wv * v.x;
        acc[r].y += wv * v.y;
        acc[r].z += wv * v.z;
        acc[r].w += wv * v.w;
      }
    }
  }

  const float4* pao4 = reinterpret_cast<const float4*>(pao);
  float4* out4 = reinterpret_cast<float4*>(out);
#pragma unroll
  for (int r = 0; r < 16; ++r) {
    const long o = (long)(r0 + r) * (Hq / 4) + c4;
    const float4 p = pao4[o];
    out4[o] = make_float4(p.x + acc[r].x, p.y + acc[r].y,
                          p.z + acc[r].z, p.w + acc[r].w);
  }
}

extern "C" void kernel_launch(void* const* d_in, const int* in_sizes, int n_in,
                              void* d_out, int out_size, void* d_ws, size_t ws_size,
                              hipStream_t stream) {
  const float* hs  = (const float*)d_in[0];   // [2,2048,4096]
  const float* pao = (const float*)d_in[1];   // [2,2048,4096]
  const float* paw = (const float*)d_in[2];   // [2,32,2048,2048]
  const float* rel = (const float*)d_in[3];   // [100]
  const float* Wq  = (const float*)d_in[4];   // [64,4096]
  const float* ak  = (const float*)d_in[5];   // [100,64]
  const float* av  = (const float*)d_in[6];   // [100,4096]
  const float* gw1 = (const float*)d_in[7];   // scalar
  const float* gb  = (const float*)d_in[8];   // scalar
  float* out = (float*)d_out;

  float* ent_ws  = (float*)d_ws;                        // 8192 floats (2 halves/row)
  float* qpart   = ent_ws + 2 * ROWS;                   // 8*4096*64 floats (8 MB)
  float* attn_ws = qpart + (long)KSPLIT * ROWS * Dq;    // 4096*100 floats

  k_entropy_part<<<ROWS * 2, 256, 0, stream>>>(paw, ent_ws);
  k_qproj<<<dim3(ROWS / RB, KSPLIT), 256, 0, stream>>>(hs, Wq, qpart);
  k_scores<<<ROWS, 128, 0, stream>>>(qpart, ak, rel, ent_ws, gw1, gb, attn_ws);
  k_aux_fuse<<<dim3(4, ROWS / 16), 256, 0, stream>>>(av, pao, attn_ws, out);
}

// Round 2
// 1516.793 us; speedup vs baseline: 1.2847x; 1.0477x over previous
//
#include <hip/hip_runtime.h>

// Problem dims (fixed by reference setup_inputs):
// B=2, S=2048, H=4096, NH=32, NS=100, D=64
#define Bq 2
#define Sq 2048
#define Hq 4096
#define NHq 32
#define NSq 100
#define Dq 64

#define ROWS (Bq * Sq)          // 4096 total (b,s) rows
#define KSPLIT 8                // k-split blocks for q-projection
#define KRANGE (Hq / KSPLIT)    // 512
#define KC 64                   // K-chunk staged in LDS
#define RB 128                  // rows per q-projection block
#define LDP (KC + 4)            // padded LDS row stride

// ---------------------------------------------------------------------------
// K1: entropy of head-averaged primary attention, 2 full rows per block.
// 2048 blocks (exactly 8/CU, all-resident, zero tail). Per head a block reads
// 16 KB CONTIGUOUS (rows s0,s0+1 x 2048 cols) before the 16 MB head-stride
// jump -> 8x longer DRAM runs / 4x fewer concurrent streams than the previous
// 4KB-run version. Same 1.07 GB total traffic. Probe: if the old version was
// DRAM-row-locality-limited this recovers 100-200 us; if it was already at
// HBM BW this is neutral.
// ---------------------------------------------------------------------------
__global__ __launch_bounds__(256) void k_entropy_pair(
    const float* __restrict__ paw, float* __restrict__ ent_ws) {
  const int blk = blockIdx.x;          // 0..2047, 2 consecutive rows each
  const int bs0 = blk * 2;
  const int b = bs0 >> 11;             // /2048 (pairs never straddle b)
  const int s0 = bs0 & 2047;
  const int t = threadIdx.x;

  const float4* base = reinterpret_cast<const float4*>(paw);
  long idx = ((long)(b * NHq) * Sq + s0) * (Sq / 4);   // (b, h=0, s0) in float4
  const long hstep = (long)Sq * (Sq / 4);              // 16 MB / 16 B

  float4 a00 = make_float4(0.f, 0.f, 0.f, 0.f);   // row s0, cols t
  float4 a01 = make_float4(0.f, 0.f, 0.f, 0.f);   // row s0, cols t+256
  float4 a10 = make_float4(0.f, 0.f, 0.f, 0.f);   // row s0+1, cols t
  float4 a11 = make_float4(0.f, 0.f, 0.f, 0.f);   // row s0+1, cols t+256
#pragma unroll 2
  for (int h = 0; h < NHq; ++h) {
    const float4 v00 = base[idx + t];
    const float4 v01 = base[idx + 256 + t];
    const float4 v10 = base[idx + 512 + t];
    const float4 v11 = base[idx + 768 + t];
    a00.x += v00.x; a00.y += v00.y; a00.z += v00.z; a00.w += v00.w;
    a01.x += v01.x; a01.y += v01.y; a01.z += v01.z; a01.w += v01.w;
    a10.x += v10.x; a10.y += v10.y; a10.z += v10.z; a10.w += v10.w;
    a11.x += v11.x; a11.y += v11.y; a11.z += v11.z; a11.w += v11.w;
    idx += hstep;
  }

  const float inv = 1.f / 32.f;
  float e0 = 0.f, e1 = 0.f, y;
  y = a00.x * inv; e0 -= y * __logf(y + 1e-10f);
  y = a00.y * inv; e0 -= y * __logf(y + 1e-10f);
  y = a00.z * inv; e0 -= y * __logf(y + 1e-10f);
  y = a00.w * inv; e0 -= y * __logf(y + 1e-10f);
  y = a01.x * inv; e0 -= y * __logf(y + 1e-10f);
  y = a01.y * inv; e0 -= y * __logf(y + 1e-10f);
  y = a01.z * inv; e0 -= y * __logf(y + 1e-10f);
  y = a01.w * inv; e0 -= y * __logf(y + 1e-10f);
  y = a10.x * inv; e1 -= y * __logf(y + 1e-10f);
  y = a10.y * inv; e1 -= y * __logf(y + 1e-10f);
  y = a10.z * inv; e1 -= y * __logf(y + 1e-10f);
  y = a10.w * inv; e1 -= y * __logf(y + 1e-10f);
  y = a11.x * inv; e1 -= y * __logf(y + 1e-10f);
  y = a11.y * inv; e1 -= y * __logf(y + 1e-10f);
  y = a11.z * inv; e1 -= y * __logf(y + 1e-10f);
  y = a11.w * inv; e1 -= y * __logf(y + 1e-10f);

#pragma unroll
  for (int off = 32; off > 0; off >>= 1) {
    e0 += __shfl_down(e0, off, 64);
    e1 += __shfl_down(e1, off, 64);
  }
  __shared__ float red[2][4];
  if ((t & 63) == 0) { red[0][t >> 6] = e0; red[1][t >> 6] = e1; }
  __syncthreads();
  if (t == 0) ent_ws[bs0]     = red[0][0] + red[0][1] + red[0][2] + red[0][3];
  if (t == 1) ent_ws[bs0 + 1] = red[1][0] + red[1][1] + red[1][2] + red[1][3];
}

// ---------------------------------------------------------------------------
// K2: q-projection as a tiled GEMM: [4096 x 4096] x [4096 x 64]^T.
// Grid 32 rowblocks x 8 ksplit = 256 blocks. Unchanged from round 1.
// ---------------------------------------------------------------------------
__global__ __launch_bounds__(256) void k_qproj(
    const float* __restrict__ hs, const float* __restrict__ Wq,
    float* __restrict__ qpart) {
  const int rblk = blockIdx.x;         // 0..31
  const int ksl  = blockIdx.y;         // 0..7
  const int t = threadIdx.x;
  const int r0 = rblk * RB;
  const int k0 = ksl * KRANGE;
  const int dg = t & 15;               // d = dg + di*16
  const int rg = t >> 4;               // row = ri*16 + rg

  __shared__ float shs[RB][LDP];       // 128 x 68 floats
  __shared__ float swq[Dq][LDP];       // 64 x 68 floats

  float acc[8][4];
#pragma unroll
  for (int i = 0; i < 8; ++i)
#pragma unroll
    for (int j = 0; j < 4; ++j) acc[i][j] = 0.f;

  const float4* hs4 = reinterpret_cast<const float4*>(hs);
  const float4* wq4 = reinterpret_cast<const float4*>(Wq);

  for (int c = 0; c < KRANGE / KC; ++c) {       // 8 chunks of 64 k
    const int kc4 = (k0 + c * KC) >> 2;
#pragma unroll
    for (int i = 0; i < 8; ++i) {
      const int idx = i * 256 + t;
      const int row = idx >> 4, col4 = idx & 15;
      const float4 v = hs4[(long)(r0 + row) * (Hq / 4) + kc4 + col4];
      *reinterpret_cast<float4*>(&shs[row][col4 * 4]) = v;
    }
#pragma unroll
    for (int i = 0; i < 4; ++i) {
      const int idx = i * 256 + t;
      const int d = idx >> 4, col4 = idx & 15;
      const float4 v = wq4[(long)d * (Hq / 4) + kc4 + col4];
      *reinterpret_cast<float4*>(&swq[d][col4 * 4]) = v;
    }
    __syncthreads();

#pragma unroll 4
    for (int kk = 0; kk < KC; kk += 4) {
      const float4 wv0 = *reinterpret_cast<const float4*>(&swq[dg     ][kk]);
      const float4 wv1 = *reinterpret_cast<const float4*>(&swq[dg + 16][kk]);
      const float4 wv2 = *reinterpret_cast<const float4*>(&swq[dg + 32][kk]);
      const float4 wv3 = *reinterpret_cast<const float4*>(&swq[dg + 48][kk]);
#pragma unroll
      for (int ri = 0; ri < 8; ++ri) {
        const float4 hv = *reinterpret_cast<const float4*>(&shs[ri * 16 + rg][kk]);
        acc[ri][0] += hv.x * wv0.x + hv.y * wv0.y + hv.z * wv0.z + hv.w * wv0.w;
        acc[ri][1] += hv.x * wv1.x + hv.y * wv1.y + hv.z * wv1.z + hv.w * wv1.w;
        acc[ri][2] += hv.x * wv2.x + hv.y * wv2.y + hv.z * wv2.z + hv.w * wv2.w;
        acc[ri][3] += hv.x * wv3.x + hv.y * wv3.y + hv.z * wv3.z + hv.w * wv3.w;
      }
    }
    __syncthreads();
  }

  float* qp = qpart + ((long)ksl * ROWS + r0) * Dq;
#pragma unroll
  for (int ri = 0; ri < 8; ++ri) {
    const int r = ri * 16 + rg;
#pragma unroll
    for (int di = 0; di < 4; ++di)
      qp[r * Dq + dg + di * 16] = acc[ri][di];
  }
}

// ---------------------------------------------------------------------------
// K2b: reduce k-split partials -> q, scores vs 100 aux keys, softmax, gate
// folded into the stored weights. ent_ws is now one value per row.
// ---------------------------------------------------------------------------
__global__ __launch_bounds__(128) void k_scores(
    const float* __restrict__ qpart, const float* __restrict__ ak,
    const float* __restrict__ rel, const float* __restrict__ ent_ws,
    const float* __restrict__ gw1p, const float* __restrict__ gbp,
    float* __restrict__ attn_ws) {
  const int row = blockIdx.x;          // 0..4095
  const int t = threadIdx.x;           // 0..127

  __shared__ float sq[Dq];
  __shared__ float ssc[128];
  __shared__ float sgate;

  if (t < Dq) {
    float q = 0.f;
#pragma unroll
    for (int ks = 0; ks < KSPLIT; ++ks)
      q += qpart[((long)ks * ROWS + row) * Dq + t];
    sq[t] = q;
  }
  if (t == 64) {
    const float ent = ent_ws[row];
    float g = 1.f / (1.f + __expf(-(gw1p[0] * ent + gbp[0])));
    if (ent < 0.5f) g = 0.f;
    else if (ent > 2.0f) g = fminf(g, 0.8f);
    sgate = g;
  }
  if (t >= NSq) ssc[t] = -1e30f;       // pad 100..127 for the softmax
  __syncthreads();

  if (t < NSq) {
    const float4* a4 = reinterpret_cast<const float4*>(ak) + t * (Dq / 4);
    const float4* q4 = reinterpret_cast<const float4*>(sq);
    float acc = 0.f;
#pragma unroll
    for (int i = 0; i < Dq / 4; ++i) {
      const float4 a = a4[i];
      const float4 q = q4[i];
      acc += a.x * q.x + a.y * q.y + a.z * q.z + a.w * q.w;
    }
    ssc[t] = acc * 0.125f + __logf(rel[t] + 1e-10f);
  }
  __syncthreads();

  if (t < 64) {
    const float s0 = ssc[t];
    const float s1 = ssc[t + 64];
    float m = fmaxf(s0, s1);
#pragma unroll
    for (int off = 1; off < 64; off <<= 1) m = fmaxf(m, __shfl_xor(m, off, 64));
    const float p0 = __expf(s0 - m);
    const float p1 = __expf(s1 - m);
    float sum = p0 + p1;
#pragma unroll
    for (int off = 1; off < 64; off <<= 1) sum += __shfl_xor(sum, off, 64);
    const float scale = sgate / sum;   // gate folded in
    float* arow = attn_ws + (long)row * NSq;
    arow[t] = p0 * scale;
    if (t + 64 < NSq) arow[t + 64] = p1 * scale;
  }
}

// ---------------------------------------------------------------------------
// K3: fused = pao + sum_n attn_ws[row][n] * aux_values[n][:]. Unchanged.
// ---------------------------------------------------------------------------
__global__ __launch_bounds__(256) void k_aux_fuse(
    const float* __restrict__ av, const float* __restrict__ pao,
    const float* __restrict__ attn_ws, float* __restrict__ out) {
  const int ht = blockIdx.x;           // 0..3
  const int rb = blockIdx.y;           // 0..255
  const int t = threadIdx.x;
  const int r0 = rb * 16;
  const int c4 = ht * 256 + t;

  const float4* av4 = reinterpret_cast<const float4*>(av);
  const float* w = attn_ws + (long)r0 * NSq;   // uniform -> scalar loads

  float4 acc[16];
#pragma unroll
  for (int r = 0; r < 16; ++r) acc[r] = make_float4(0.f, 0.f, 0.f, 0.f);

  for (int n = 0; n < NSq; n += 4) {
#pragma unroll
    for (int j = 0; j < 4; ++j) {
      const float4 v = av4[(long)(n + j) * (Hq / 4) + c4];
#pragma unroll
      for (int r = 0; r < 16; ++r) {
        const float wv = w[r * NSq + n + j];
        acc[r].x += wv * v.x;
        acc[r].y += wv * v.y;
        acc[r].z += wv * v.z;
        acc[r].w += wv * v.w;
      }
    }
  }

  const float4* pao4 = reinterpret_cast<const float4*>(pao);
  float4* out4 = reinterpret_cast<float4*>(out);
#pragma unroll
  for (int r = 0; r < 16; ++r) {
    const long o = (long)(r0 + r) * (Hq / 4) + c4;
    const float4 p = pao4[o];
    out4[o] = make_float4(p.x + acc[r].x, p.y + acc[r].y,
                          p.z + acc[r].z, p.w + acc[r].w);
  }
}

extern "C" void kernel_launch(void* const* d_in, const int* in_sizes, int n_in,
                              void* d_out, int out_size, void* d_ws, size_t ws_size,
                              hipStream_t stream) {
  const float* hs  = (const float*)d_in[0];   // [2,2048,4096]
  const float* pao = (const float*)d_in[1];   // [2,2048,4096]
  const float* paw = (const float*)d_in[2];   // [2,32,2048,2048]
  const float* rel = (const float*)d_in[3];   // [100]
  const float* Wq  = (const float*)d_in[4];   // [64,4096]
  const float* ak  = (const float*)d_in[5];   // [100,64]
  const float* av  = (const float*)d_in[6];   // [100,4096]
  const float* gw1 = (const float*)d_in[7];   // scalar
  const float* gb  = (const float*)d_in[8];   // scalar
  float* out = (float*)d_out;

  float* ent_ws  = (float*)d_ws;                        // ROWS floats (slack to 2*ROWS)
  float* qpart   = ent_ws + 2 * ROWS;                   // 8*4096*64 floats (8 MB)
  float* attn_ws = qpart + (long)KSPLIT * ROWS * Dq;    // 4096*100 floats

  k_entropy_pair<<<ROWS / 2, 256, 0, stream>>>(paw, ent_ws);
  k_qproj<<<dim3(ROWS / RB, KSPLIT), 256, 0, stream>>>(hs, Wq, qpart);
  k_scores<<<ROWS, 128, 0, stream>>>(qpart, ak, rel, ent_ws, gw1, gb, attn_ws);
  k_aux_fuse<<<dim3(4, ROWS / 16), 256, 0, stream>>>(av, pao, attn_ws, out);
}